// Round 18
// baseline (51.068 us; speedup 1.0000x reference)
//
#include <hip/hip_runtime.h>
#include <hip/hip_bf16.h>

#define BB 8
#define NN 1024
#define HH 512
#define NEG 0.2f

typedef float f32x4 __attribute__((ext_vector_type(4)));
typedef short bf16x8 __attribute__((ext_vector_type(8)));
typedef int i32x4 __attribute__((ext_vector_type(4)));
typedef unsigned int u32;

__device__ __forceinline__ unsigned short f2bf(float f) {
    union { float f; u32 u; } a; a.f = f;
    u32 u = a.u;
    u += 0x7fffu + ((u >> 16) & 1u);   // round-to-nearest-even
    return (unsigned short)(u >> 16);
}

__device__ __forceinline__ void gload16(const void* g, void* l) {
    __builtin_amdgcn_global_load_lds(
        (const __attribute__((address_space(1))) unsigned int*)g,
        (__attribute__((address_space(3))) unsigned int*)l, 16, 0, 0);
}

// Kernel 1: per (batch, 16-row j-tile): s_src/s_dst dots + X^T bf16 [b][h][j]
__global__ __launch_bounds__(512) void prep_kernel(
    const float* __restrict__ x, const float* __restrict__ wsrc,
    const float* __restrict__ wdst, float* __restrict__ ssrc,
    float* __restrict__ sdst, unsigned short* __restrict__ xt)
{
    __shared__ __align__(16) unsigned short lt[16][528];

    int bid = blockIdx.x;
    int b = bid & 7;
    int j0 = (bid >> 3) * 16;
    int t = threadIdx.x;
    int r = t >> 5;            // 0..15: row in tile (32 threads per row)
    int l = t & 31;

    const float* xrow = x + ((size_t)(b * NN + j0 + r)) * HH;
    float psrc = 0.f, pdst = 0.f;
    #pragma unroll
    for (int q = 0; q < 4; ++q) {
        int h = q * 128 + l * 4;
        f32x4 v = __builtin_nontemporal_load((const f32x4*)(xrow + h));
        f32x4 a = *(const f32x4*)(wsrc + h);
        f32x4 d = *(const f32x4*)(wdst + h);
        psrc += v[0]*a[0] + v[1]*a[1] + v[2]*a[2] + v[3]*a[3];
        pdst += v[0]*d[0] + v[1]*d[1] + v[2]*d[2] + v[3]*d[3];
        u32 lo = (u32)f2bf(v[0]) | ((u32)f2bf(v[1]) << 16);
        u32 hi = (u32)f2bf(v[2]) | ((u32)f2bf(v[3]) << 16);
        *(u32*)&lt[r][h + 0] = lo;
        *(u32*)&lt[r][h + 2] = hi;
    }
    #pragma unroll
    for (int k = 1; k < 32; k <<= 1) {
        psrc += __shfl_xor(psrc, k);
        pdst += __shfl_xor(pdst, k);
    }
    if (l == 0) {
        ssrc[b * NN + j0 + r] = psrc;
        sdst[b * NN + j0 + r] = pdst;
    }
    __syncthreads();

    unsigned short v[16];
    #pragma unroll
    for (int rr = 0; rr < 16; ++rr) v[rr] = lt[rr][t];
    unsigned short* dst = xt + ((size_t)(b * HH + t)) * NN + j0;
    #pragma unroll
    for (int q = 0; q < 2; ++q) {
        bf16x8 pk;
        #pragma unroll
        for (int e = 0; e < 8; ++e) pk[e] = (short)v[q*8 + e];
        *(bf16x8*)(dst + q * 8) = pk;
    }
}

// Kernel 2: FUSED esum + PV, v4. Block = (b, 32-row i-tile), grid 256, 512 thr.
// Sweep 1: adj streamed via gload_lds 4-slot ring, BARRIER-FREE (each thread
//   reads back exactly the 16B its own gload wrote: dest = t*16 lane-linear),
//   per-wave counted vmcnt(3); E (unnormalized, <=3e3) -> 64KB swizzled LDS;
//   row sums via 16-lane shuffle -> inv_l in LDS.
// Sweep 2: R9/R13-verified barrier-free GEMM: A register-direct from L2-hot
//   XT[b] (XCD-affine), B from swizzled LDS, 16x16x32 MFMA; epilogue * inv_l.
__global__ __launch_bounds__(512) void fgat_kernel(
    const float* __restrict__ ssrc, const float* __restrict__ sdst,
    const int* __restrict__ adj, const float* __restrict__ bptr,
    const unsigned short* __restrict__ xt, float* __restrict__ out)
{
    __shared__ __align__(16) unsigned short Pl[32 * NN];   // 64KB: E, swizzled
    __shared__ __align__(16) int adjb[4 * 2048];           // 32KB: 4-slot adj ring
    __shared__ __align__(16) float sd[NN];                 // 4KB
    __shared__ float ss[32];
    __shared__ float inv_l[32];

    int bid = blockIdx.x;
    int b = bid & 7;               // XCD-affine: XT[b] hot in this XCD's L2
    int i0 = (bid >> 3) * 32;
    int t = threadIdx.x;
    int lane = t & 63;
    int w = t >> 6;                // wave 0..7: h-chunk of 64 in sweep 2
    int il = t >> 4;               // 0..31: i-row (16 threads per row)
    int jq = t & 15;               // j-quad group within each 64-j chunk

    *(float2*)&sd[t * 2] = *(const float2*)&sdst[b * NN + t * 2];
    if (t < 32) ss[t] = ssrc[b * NN + i0 + t];
    __syncthreads();               // also drains vmcnt -> clean count for ring

    // ---- Sweep 1: async adj ring ----
    int ig = i0 + il;
    float si = ss[il] + bptr[0];
    const int* arow = adj + ((size_t)(b * NN + ig)) * NN + jq * 4;
    int* myslot = adjb + t * 4;    // this thread's 16B; slot stride 2048 ints

    #pragma unroll
    for (int s = 0; s < 4; ++s)
        gload16(arow + s * 64, myslot + s * 2048);

    float sum = 0.f;
    #pragma unroll
    for (int T = 0; T < 16; ++T) {
        // wait for chunk T's load (up to 3 newer stay in flight)
        if (T <= 12)      asm volatile("s_waitcnt vmcnt(3)" ::: "memory");
        else if (T == 13) asm volatile("s_waitcnt vmcnt(2)" ::: "memory");
        else if (T == 14) asm volatile("s_waitcnt vmcnt(1)" ::: "memory");
        else              asm volatile("s_waitcnt vmcnt(0)" ::: "memory");
        __builtin_amdgcn_sched_barrier(0);
        i32x4 a4 = *(const i32x4*)(myslot + (T & 3) * 2048);
        asm volatile("s_waitcnt lgkmcnt(0)" ::: "memory");   // a4 in regs: WAR-safe
        __builtin_amdgcn_sched_barrier(0);
        if (T + 4 < 16) gload16(arow + (T + 4) * 64, myslot + (T & 3) * 2048);

        int j = T * 64 + jq * 4;
        f32x4 sv = *(const f32x4*)&sd[j];
        float e[4];
        #pragma unroll
        for (int k = 0; k < 4; ++k) {
            float s = si + sv[k];
            float lk = fmaxf(s, NEG * s);          // leaky relu
            float ev = __expf(lk);                 // no max-sub: |s|<~8 -> safe
            e[k] = (a4[k] != 0 || (j + k) == ig) ? ev : 0.f;
            sum += e[k];
        }
        u32 lo = (u32)f2bf(e[0]) | ((u32)f2bf(e[1]) << 16);
        u32 hi = (u32)f2bf(e[2]) | ((u32)f2bf(e[3]) << 16);
        int byte = ((il * NN + j) * 2) ^ ((il & 7) << 4);
        *(uint2*)((char*)Pl + byte) = make_uint2(lo, hi);
    }
    #pragma unroll
    for (int k = 1; k < 16; k <<= 1) sum += __shfl_xor(sum, k);
    if ((t & 15) == 0) inv_l[il] = 1.f / sum;
    __syncthreads();   // E + inv_l visible to all waves

    // ---- Sweep 2: barrier-free GEMM (R9-verified). out^T: M=h, N=i, K=j ----
    int g = lane >> 4;
    int ln = lane & 15;
    const unsigned short* abase = xt + ((size_t)(b * HH + w * 64 + ln)) * NN + g * 8;

    // B read bases: XOR spans bits 4-6 -> kk*64, g*16 inside the XOR (R8 lesson);
    // js*128 (bits 7+) added at use, carry-free.
    const char* pb[2][2];
    #pragma unroll
    for (int nb = 0; nb < 2; ++nb) {
        int row = nb * 16 + ln;
        #pragma unroll
        for (int kk = 0; kk < 2; ++kk)
            pb[nb][kk] = (const char*)Pl + ((row * 2048 + kk * 64 + g * 16) ^ ((row & 7) << 4));
    }

    f32x4 acc[4][2];
    #pragma unroll
    for (int ma = 0; ma < 4; ++ma)
        #pragma unroll
        for (int nb = 0; nb < 2; ++nb)
            acc[ma][nb] = (f32x4){0.f, 0.f, 0.f, 0.f};

    #pragma unroll
    for (int js = 0; js < 16; ++js) {
        bf16x8 af[4][2], bfr[2][2];
        #pragma unroll
        for (int ma = 0; ma < 4; ++ma)
            #pragma unroll
            for (int kk = 0; kk < 2; ++kk)
                af[ma][kk] = *(const bf16x8*)(abase + (size_t)(ma * 16) * NN + js * 64 + kk * 32);
        #pragma unroll
        for (int nb = 0; nb < 2; ++nb)
            #pragma unroll
            for (int kk = 0; kk < 2; ++kk)
                bfr[nb][kk] = *(const bf16x8*)(pb[nb][kk] + js * 128);
        #pragma unroll
        for (int kk = 0; kk < 2; ++kk)
            #pragma unroll
            for (int ma = 0; ma < 4; ++ma)
                #pragma unroll
                for (int nb = 0; nb < 2; ++nb)
                    acc[ma][nb] = __builtin_amdgcn_mfma_f32_16x16x32_bf16(af[ma][kk], bfr[nb][kk], acc[ma][nb], 0, 0, 0);
    }

    // D: h = w*64 + ma*16 + g*4 + r, i = i0 + nb*16 + ln; scale by inv_l[i]
    #pragma unroll
    for (int nb = 0; nb < 2; ++nb) {
        int i = i0 + nb * 16 + ln;
        float il_ = inv_l[nb * 16 + ln];
        #pragma unroll
        for (int ma = 0; ma < 4; ++ma) {
            f32x4 v = acc[ma][nb];
            v *= il_;
            float* dst = out + ((size_t)(b * NN + i)) * HH + w * 64 + ma * 16 + g * 4;
            __builtin_nontemporal_store(v, (f32x4*)dst);
        }
    }
}

extern "C" void kernel_launch(void* const* d_in, const int* in_sizes, int n_in,
                              void* d_out, int out_size, void* d_ws, size_t ws_size,
                              hipStream_t stream) {
    const float* x    = (const float*)d_in[0];
    const int*   adj  = (const int*)d_in[1];
    const float* wsrc = (const float*)d_in[2];
    const float* wdst = (const float*)d_in[3];
    const float* bias = (const float*)d_in[4];
    float* out = (float*)d_out;

    // ws layout: ssrc(32KB) | sdst(32KB) | XT bf16 (8MB)
    float* ssrc = (float*)d_ws;
    float* sdst = ssrc + BB * NN;
    unsigned short* xt = (unsigned short*)(sdst + BB * NN);

    prep_kernel<<<dim3(BB * (NN / 16)), dim3(512), 0, stream>>>(x, wsrc, wdst, ssrc, sdst, xt);
    fgat_kernel<<<dim3(BB * (NN / 32)), dim3(512), 0, stream>>>(ssrc, sdst, adj, bias, xt, out);
}